// Round 7
// baseline (90.084 us; speedup 1.0000x reference)
//
#include <hip/hip_runtime.h>

#define B_SZ   1024
#define OUT_SZ 512
#define IN_SZ  1024
#define KSPLIT 8
#define KSL    (IN_SZ / KSPLIT)   // 128 raw k per block
#define NSTEP  (KSL / 32)         // 4 MFMA k-steps of 32

typedef __bf16 bf16x8 __attribute__((ext_vector_type(8)));
typedef float  f32x4  __attribute__((ext_vector_type(4)));

// Pure-register streaming MFMA kernel: no LDS, no barriers.
// Each wave owns a 32x32 output quadrant; fragments built in-register from
// coalesced float4 loads (lane pattern: row=lane&15, k=quad*8+j — the
// m120-verified A-operand layout, same for B with row=o).
// z = sum_k u^2*x^2 + (-2u^2w)*x  via 2 GEMM segments; r = sum (uw)^2 in
// fp32 VALU + quad shfl-reduce (exact, cheaper than a bias MFMA).
__global__ __launch_bounds__(256) void rbf_fused(
    const float* __restrict__ x, const float* __restrict__ w,
    const float* __restrict__ u, float* __restrict__ part)
{
    const int bid = blockIdx.x;
    // XCD swizzle: dispatch round-robins consecutive ids over 8 XCDs, so
    // bid&7 == XCD. Fix the o-tile per XCD -> u,w slice stays hot in its L2.
    const int yt = bid & 7;            // o-tile (8)
    const int xt = (bid >> 3) & 15;    // b-tile (16)
    const int kz = bid >> 7;           // k-slice (8)

    const int lane  = threadIdx.x & 63;
    const int wv    = threadIdx.x >> 6;
    const int wm    = wv >> 1, wn = wv & 1;
    const int row16 = lane & 15;
    const int quad  = lane >> 4;

    const int mBase = xt * 64 + wm * 32;
    const int nBase = yt * 64 + wn * 32;
    const size_t kOff = (size_t)kz * KSL + quad * 8;

    const float* px0 = &x[(size_t)(mBase + row16) * IN_SZ + kOff];
    const float* px1 = px0 + (size_t)16 * IN_SZ;
    const float* pu0 = &u[(size_t)(nBase + row16) * IN_SZ + kOff];
    const float* pu1 = pu0 + (size_t)16 * IN_SZ;
    const float* pw0 = &w[(size_t)(nBase + row16) * IN_SZ + kOff];
    const float* pw1 = pw0 + (size_t)16 * IN_SZ;

    f32x4 acc[2][2] = {};
    float r0 = 0.f, r1 = 0.f;

    #pragma unroll 2
    for (int s = 0; s < NSTEP; ++s) {
        const int ko = s * 32;
        const float4 xa0 = *(const float4*)&px0[ko];
        const float4 xb0 = *(const float4*)&px0[ko + 4];
        const float4 xa1 = *(const float4*)&px1[ko];
        const float4 xb1 = *(const float4*)&px1[ko + 4];
        const float4 ua0 = *(const float4*)&pu0[ko];
        const float4 ub0 = *(const float4*)&pu0[ko + 4];
        const float4 ua1 = *(const float4*)&pu1[ko];
        const float4 ub1 = *(const float4*)&pu1[ko + 4];
        const float4 wa0 = *(const float4*)&pw0[ko];
        const float4 wb0 = *(const float4*)&pw0[ko + 4];
        const float4 wa1 = *(const float4*)&pw1[ko];
        const float4 wb1 = *(const float4*)&pw1[ko + 4];

        const float xe0[8] = {xa0.x, xa0.y, xa0.z, xa0.w, xb0.x, xb0.y, xb0.z, xb0.w};
        const float xe1[8] = {xa1.x, xa1.y, xa1.z, xa1.w, xb1.x, xb1.y, xb1.z, xb1.w};
        const float ue0[8] = {ua0.x, ua0.y, ua0.z, ua0.w, ub0.x, ub0.y, ub0.z, ub0.w};
        const float ue1[8] = {ua1.x, ua1.y, ua1.z, ua1.w, ub1.x, ub1.y, ub1.z, ub1.w};
        const float we0[8] = {wa0.x, wa0.y, wa0.z, wa0.w, wb0.x, wb0.y, wb0.z, wb0.w};
        const float we1[8] = {wa1.x, wa1.y, wa1.z, wa1.w, wb1.x, wb1.y, wb1.z, wb1.w};

        bf16x8 aX2_0, aX_0, aX2_1, aX_1, bU2_0, bM_0, bU2_1, bM_1;
        #pragma unroll
        for (int e = 0; e < 8; ++e) {
            const float xv0 = xe0[e], xv1 = xe1[e];
            aX2_0[e] = (__bf16)(xv0 * xv0);   aX_0[e] = (__bf16)xv0;
            aX2_1[e] = (__bf16)(xv1 * xv1);   aX_1[e] = (__bf16)xv1;

            const float uu0 = ue0[e], ww0 = we0[e];
            const float u20 = uu0 * uu0, uw0 = uu0 * ww0;
            bU2_0[e] = (__bf16)u20;
            bM_0[e]  = (__bf16)(-2.f * (u20 * ww0));
            r0 = fmaf(uw0, uw0, r0);

            const float uu1 = ue1[e], ww1 = we1[e];
            const float u21 = uu1 * uu1, uw1 = uu1 * ww1;
            bU2_1[e] = (__bf16)u21;
            bM_1[e]  = (__bf16)(-2.f * (u21 * ww1));
            r1 = fmaf(uw1, uw1, r1);
        }

        acc[0][0] = __builtin_amdgcn_mfma_f32_16x16x32_bf16(aX2_0, bU2_0, acc[0][0], 0, 0, 0);
        acc[0][1] = __builtin_amdgcn_mfma_f32_16x16x32_bf16(aX2_0, bU2_1, acc[0][1], 0, 0, 0);
        acc[1][0] = __builtin_amdgcn_mfma_f32_16x16x32_bf16(aX2_1, bU2_0, acc[1][0], 0, 0, 0);
        acc[1][1] = __builtin_amdgcn_mfma_f32_16x16x32_bf16(aX2_1, bU2_1, acc[1][1], 0, 0, 0);
        acc[0][0] = __builtin_amdgcn_mfma_f32_16x16x32_bf16(aX_0, bM_0, acc[0][0], 0, 0, 0);
        acc[0][1] = __builtin_amdgcn_mfma_f32_16x16x32_bf16(aX_0, bM_1, acc[0][1], 0, 0, 0);
        acc[1][0] = __builtin_amdgcn_mfma_f32_16x16x32_bf16(aX_1, bM_0, acc[1][0], 0, 0, 0);
        acc[1][1] = __builtin_amdgcn_mfma_f32_16x16x32_bf16(aX_1, bM_1, acc[1][1], 0, 0, 0);
    }

    // k is spread over quads: sum r across quad bits (lane^16, lane^32)
    r0 += __shfl_xor(r0, 16);  r0 += __shfl_xor(r0, 32);
    r1 += __shfl_xor(r1, 16);  r1 += __shfl_xor(r1, 32);

    // C/D: col = lane&15 (o), row = quad*4 + reg (b)   [m89-verified]
    #pragma unroll
    for (int mi = 0; mi < 2; ++mi) {
        const int b = mBase + mi * 16 + quad * 4;
        #pragma unroll
        for (int ni = 0; ni < 2; ++ni) {
            const int o = nBase + ni * 16 + row16;
            const float rr = ni ? r1 : r0;
            #pragma unroll
            for (int rg = 0; rg < 4; ++rg)
                part[((size_t)kz * B_SZ + (b + rg)) * OUT_SZ + o] = acc[mi][ni][rg] + rr;
        }
    }
}

// z = sum_kz part, out = a + exp(-z)*(1-2a). float4-vectorized.
__global__ __launch_bounds__(256) void rbf_reduce(
    const float* __restrict__ part, const float* __restrict__ andor,
    float* __restrict__ out)
{
    const int i4 = blockIdx.x * 256 + threadIdx.x;      // float4 index
    const int base = i4 * 4;
    if (base < B_SZ * OUT_SZ) {
        float4 z = make_float4(0.f, 0.f, 0.f, 0.f);
        #pragma unroll
        for (int kz = 0; kz < KSPLIT; ++kz) {
            const float4 p = *(const float4*)&part[(size_t)kz * (B_SZ * OUT_SZ) + base];
            z.x += p.x; z.y += p.y; z.z += p.z; z.w += p.w;
        }
        const float4 a = *(const float4*)&andor[base & (OUT_SZ - 1)];
        float4 o;
        o.x = fmaf(__expf(-z.x), 1.f - 2.f * a.x, a.x);
        o.y = fmaf(__expf(-z.y), 1.f - 2.f * a.y, a.y);
        o.z = fmaf(__expf(-z.z), 1.f - 2.f * a.z, a.z);
        o.w = fmaf(__expf(-z.w), 1.f - 2.f * a.w, a.w);
        *(float4*)&out[base] = o;
    }
}

extern "C" void kernel_launch(void* const* d_in, const int* in_sizes, int n_in,
                              void* d_out, int out_size, void* d_ws, size_t ws_size,
                              hipStream_t stream) {
    const float* x = (const float*)d_in[0];   // [B, IN]
    const float* w = (const float*)d_in[1];   // [OUT, IN]
    const float* u = (const float*)d_in[2];   // [OUT, IN]
    const float* a = (const float*)d_in[3];   // [1, OUT]
    float* out = (float*)d_out;               // [B, OUT]

    float* part = (float*)d_ws;               // [KSPLIT][B][OUT] f32 = 16.8 MB

    rbf_fused<<<dim3(16 * 8 * KSPLIT), dim3(256), 0, stream>>>(x, w, u, part);
    rbf_reduce<<<dim3((B_SZ * OUT_SZ / 4 + 255) / 256), dim3(256), 0, stream>>>(part, a, out);
}

// Round 8
// 80.518 us; speedup vs baseline: 1.1188x; 1.1188x over previous
//
#include <hip/hip_runtime.h>

#define B_SZ   1024
#define OUT_SZ 512
#define IN_SZ  1024
#define CH     64
#define NCHUNK (IN_SZ / CH)      // 16
#define MBT    32                // b rows per block
#define NBT    64                // o rows per block

typedef __bf16 bf16x8 __attribute__((ext_vector_type(8)));
typedef __bf16 bf16x4 __attribute__((ext_vector_type(4)));
typedef float  f32x4  __attribute__((ext_vector_type(4)));

// Fragment-native LDS, lane-contiguous 16B slots (conflict-free b128 reads):
//   A[seg:2][s:2][frag:2][lane:64][8 bf16]  = 8 KB per buffer
//   B[seg:3][s:2][frag:4][lane:64][8 bf16]  = 24 KB per buffer
// seg A: 0=x^2, 1=x   seg B: 0=u^2, 1=-2u^2w, 2=(uw)^2
#define A_IDX(seg,s,fr,ln) (((((seg)*2+(s))*2+(fr))*64 + (ln))*8)
#define B_IDX(seg,s,fr,ln) (((((seg)*2+(s))*4+(fr))*64 + (ln))*8)

// ONE kernel: grid 256 = 1 block/CU (yt=bid&7 pins o-slice to an XCD's L2),
// 512 threads = 8 waves, wave-tile 16x16, full K per block, no workspace,
// exp/mix epilogue fused, double-buffered LDS w/ 1 barrier/chunk and
// prefetch-distance-2 register banks.
__global__ __launch_bounds__(512) void rbf_one(
    const float* __restrict__ x, const float* __restrict__ w,
    const float* __restrict__ u, const float* __restrict__ andor,
    float* __restrict__ out)
{
    __shared__ __bf16 As[2][4096];
    __shared__ __bf16 Bs[2][12288];

    const int t    = threadIdx.x;
    const int lane = t & 63;
    const int wv   = t >> 6;          // 0..7
    const int wm   = wv >> 2;         // A frag (b 16-row half)
    const int wn   = wv & 3;          // B frag (o 16-row quarter)
    const int bid  = blockIdx.x;
    const int yt   = bid & 7;         // o-tile == XCD id
    const int xt   = bid >> 3;        // b-tile 0..31
    const int mBase = xt * MBT;
    const int nBase = yt * NBT;

    float4 xr[2], ur[2][2], wr[2][2]; // 2 register banks (prefetch depth 2)

    // dense coalesced loads: wave sweeps 4 rows x 256B (x), 8 rows (u/w)
    auto load_regs = [&](int bank, int c) {
        const int k0 = c * CH;
        xr[bank] = *(const float4*)&x[(size_t)(mBase + (t >> 4)) * IN_SZ + k0 + (t & 15) * 4];
        #pragma unroll
        for (int i = 0; i < 2; ++i) {
            int f = t * 2 + i;
            int row = f >> 4, kq = f & 15;
            size_t g = (size_t)(nBase + row) * IN_SZ + k0 + kq * 4;
            ur[bank][i] = *(const float4*)&u[g];
            wr[bank][i] = *(const float4*)&w[g];
        }
    };

    // convert in-register and write fragment-order bf16 to LDS
    auto cw = [&](int bank, int bufi) {
        {
            int row = t >> 4, kq = t & 15;
            int s = kq >> 3, j0 = (kq & 1) * 4;
            int sl = ((kq >> 1) & 3) * 16 + (row & 15);
            int fr = row >> 4;
            float e[4] = {xr[bank].x, xr[bank].y, xr[bank].z, xr[bank].w};
            bf16x4 a2, a1;
            #pragma unroll
            for (int q = 0; q < 4; ++q) { a2[q] = (__bf16)(e[q] * e[q]); a1[q] = (__bf16)e[q]; }
            *(bf16x4*)&As[bufi][A_IDX(0, s, fr, sl) + j0] = a2;
            *(bf16x4*)&As[bufi][A_IDX(1, s, fr, sl) + j0] = a1;
        }
        #pragma unroll
        for (int i = 0; i < 2; ++i) {
            int f = t * 2 + i;
            int row = f >> 4, kq = f & 15;
            int s = kq >> 3, j0 = (kq & 1) * 4;
            int sl = ((kq >> 1) & 3) * 16 + (row & 15);
            int fr = row >> 4;
            float ue[4] = {ur[bank][i].x, ur[bank][i].y, ur[bank][i].z, ur[bank][i].w};
            float we[4] = {wr[bank][i].x, wr[bank][i].y, wr[bank][i].z, wr[bank][i].w};
            bf16x4 b0, b1, b2;
            #pragma unroll
            for (int q = 0; q < 4; ++q) {
                float u2 = ue[q] * ue[q];
                float uw = ue[q] * we[q];
                b0[q] = (__bf16)u2;
                b1[q] = (__bf16)(-2.f * u2 * we[q]);
                b2[q] = (__bf16)(uw * uw);
            }
            *(bf16x4*)&Bs[bufi][B_IDX(0, s, fr, sl) + j0] = b0;
            *(bf16x4*)&Bs[bufi][B_IDX(1, s, fr, sl) + j0] = b1;
            *(bf16x4*)&Bs[bufi][B_IDX(2, s, fr, sl) + j0] = b2;
        }
    };

    f32x4 acc = {}, accr = {};
    bf16x8 ones;
    #pragma unroll
    for (int j = 0; j < 8; ++j) ones[j] = (__bf16)1.f;

    load_regs(0, 0);
    load_regs(1, 1);
    cw(0, 0);
    __syncthreads();

    for (int c = 0; c < NCHUNK; ++c) {
        const int bufi = c & 1;
        if (c + 2 < NCHUNK) load_regs(c & 1, c + 2);   // bank (c+2)&1 == c&1; in flight
                                                       // across this whole chunk
        #pragma unroll
        for (int s = 0; s < 2; ++s) {
            bf16x8 a2 = *(const bf16x8*)&As[bufi][A_IDX(0, s, wm, lane)];
            bf16x8 a1 = *(const bf16x8*)&As[bufi][A_IDX(1, s, wm, lane)];
            bf16x8 b0 = *(const bf16x8*)&Bs[bufi][B_IDX(0, s, wn, lane)];
            bf16x8 b1 = *(const bf16x8*)&Bs[bufi][B_IDX(1, s, wn, lane)];
            bf16x8 b2 = *(const bf16x8*)&Bs[bufi][B_IDX(2, s, wn, lane)];
            acc  = __builtin_amdgcn_mfma_f32_16x16x32_bf16(a2,   b0, acc,  0, 0, 0);
            acc  = __builtin_amdgcn_mfma_f32_16x16x32_bf16(a1,   b1, acc,  0, 0, 0);
            accr = __builtin_amdgcn_mfma_f32_16x16x32_bf16(ones, b2, accr, 0, 0, 0);
        }
        if (c + 1 < NCHUNK) cw((c + 1) & 1, bufi ^ 1); // write other buffer
        __syncthreads();                                // one barrier per chunk
    }

    // C/D: col = lane&15 (o), row = quad*4 + reg (b)  [m89-verified]
    // accr rows all equal r[o] = sum (uw)^2.
    const int quad = lane >> 4, col = lane & 15;
    const int o    = nBase + wn * 16 + col;
    const float a  = andor[o];
    const float s1 = 1.f - 2.f * a;
    const int  b0r = mBase + wm * 16 + quad * 4;
    #pragma unroll
    for (int r = 0; r < 4; ++r) {
        float zz = acc[r] + accr[r];
        out[(size_t)(b0r + r) * OUT_SZ + o] = fmaf(__expf(-zz), s1, a);
    }
}

extern "C" void kernel_launch(void* const* d_in, const int* in_sizes, int n_in,
                              void* d_out, int out_size, void* d_ws, size_t ws_size,
                              hipStream_t stream) {
    const float* x = (const float*)d_in[0];   // [B, IN]
    const float* w = (const float*)d_in[1];   // [OUT, IN]
    const float* u = (const float*)d_in[2];   // [OUT, IN]
    const float* a = (const float*)d_in[3];   // [1, OUT]
    float* out = (float*)d_out;               // [B, OUT]

    rbf_one<<<dim3((B_SZ / MBT) * (OUT_SZ / NBT)), dim3(512), 0, stream>>>(x, w, u, a, out);
}

// Round 9
// 75.535 us; speedup vs baseline: 1.1926x; 1.0660x over previous
//
#include <hip/hip_runtime.h>

#define B_SZ   1024
#define OUT_SZ 512
#define IN_SZ  1024

#define MB 64                 // b-rows per block
#define NB 64                 // o-rows per block
#define KSPLIT 8
#define KSL (IN_SZ / KSPLIT)  // 128 raw k per block
#define CH  64                // raw k per chunk
#define NCH (KSL / CH)        // 2 chunks

typedef __bf16 bf16x8 __attribute__((ext_vector_type(8)));
typedef __bf16 bf16x4 __attribute__((ext_vector_type(4)));
typedef float  f32x4  __attribute__((ext_vector_type(4)));

// LDS fragment-native bf16 tiles: [seg][s][frag16][slot][j]
//   seg A: 0=x^2, 1=x   seg B: 0=u^2, 1=-2u^2w   ((uw)^2 now via fp32 VALU)
#define A_IDX(seg, s, mf, slot) (((((seg)*2 + (s))*4 + (mf))*64 + (slot))*8)
#define B_IDX(seg, s, nf, slot) (((((seg)*2 + (s))*4 + (nf))*64 + (slot))*8)

// R6 skeleton, 4 blocks/CU (KSPLIT=8, 32.3 KB LDS), r-bias moved to VALU.
__global__ __launch_bounds__(256) void rbf_fused(
    const float* __restrict__ x, const float* __restrict__ w,
    const float* __restrict__ u, float* __restrict__ part)
{
    __shared__ __bf16 Asm[2 * 2 * 4 * 64 * 8];   // 16 KB
    __shared__ __bf16 Bsm[2 * 2 * 4 * 64 * 8];   // 16 KB
    __shared__ float  Rsm[64];                   // r[o] partial for this k-slice

    const int t     = threadIdx.x;
    const int lane  = t & 63;
    const int wv    = t >> 6;
    const int wm    = wv >> 1;                   // wave quadrant in m
    const int wn    = wv & 1;                    // wave quadrant in n
    const int bid   = blockIdx.x;
    // XCD swizzle: bid&7 == XCD -> o-slice's u/w stays hot in that XCD's L2
    const int yt    = bid & 7;                   // o-tile (8)
    const int xt    = (bid >> 3) & 15;           // b-tile (16)
    const int kz    = bid >> 7;                  // k-slice (8)
    const int mBase = xt * MB;
    const int nBase = yt * NB;
    const int kBase = kz * KSL;

    f32x4 acc[2][2] = {};
    float r_acc[4] = {0.f, 0.f, 0.f, 0.f};       // (uw)^2 partials, row = i*16+(t>>4)

    float4 xr[4], ur[4], wr[4];

    // coalesced: per i, lanes sweep 16 float4 (256 B) per row, 4 rows/wave
    auto load_regs = [&](int c) {
        #pragma unroll
        for (int i = 0; i < 4; ++i) {
            int id  = i * 256 + t;
            int row = id >> 4;
            int gk  = kBase + c * CH + (id & 15) * 4;
            xr[i] = *(const float4*)&x[(size_t)(mBase + row) * IN_SZ + gk];
            ur[i] = *(const float4*)&u[(size_t)(nBase + row) * IN_SZ + gk];
            wr[i] = *(const float4*)&w[(size_t)(nBase + row) * IN_SZ + gk];
        }
    };

    auto write_lds = [&]() {
        #pragma unroll
        for (int i = 0; i < 4; ++i) {
            int id    = i * 256 + t;
            int row   = id >> 4;
            int row16 = row & 15;
            int frag  = row >> 4;
            int kl    = (id & 15) * 4;
            int s     = kl >> 5;
            int quad  = (kl >> 3) & 3;
            int j0    = kl & 7;                  // 0 or 4
            int slot  = quad * 16 + ((row16 ^ quad) & 15);

            float xv[4]  = {xr[i].x, xr[i].y, xr[i].z, xr[i].w};
            float uv[4]  = {ur[i].x, ur[i].y, ur[i].z, ur[i].w};
            float wv4[4] = {wr[i].x, wr[i].y, wr[i].z, wr[i].w};
            bf16x4 a0, a1, b0, b1;
            #pragma unroll
            for (int e = 0; e < 4; ++e) {
                float xe = xv[e], ue = uv[e], we = wv4[e];
                float u2 = ue * ue;
                float uw = ue * we;
                a0[e] = (__bf16)(xe * xe);
                a1[e] = (__bf16)xe;
                b0[e] = (__bf16)u2;
                b1[e] = (__bf16)(-2.f * u2 * we);
                r_acc[i] = fmaf(uw, uw, r_acc[i]);   // exact fp32 bias term
            }
            *(bf16x4*)&Asm[A_IDX(0, s, frag, slot) + j0] = a0;
            *(bf16x4*)&Asm[A_IDX(1, s, frag, slot) + j0] = a1;
            *(bf16x4*)&Bsm[B_IDX(0, s, frag, slot) + j0] = b0;
            *(bf16x4*)&Bsm[B_IDX(1, s, frag, slot) + j0] = b1;
        }
    };

    const int r_quad = lane >> 4;
    const int r_slot = r_quad * 16 + (((lane & 15) ^ r_quad) & 15);
    const int mf0 = wm * 2, nf0 = wn * 2;

    load_regs(0);

    for (int c = 0; c < NCH; ++c) {
        __syncthreads();                         // prev compute done with LDS
        write_lds();
        __syncthreads();
        if (c + 1 < NCH) load_regs(c + 1);       // in flight across MFMA phase

        #pragma unroll
        for (int seg = 0; seg < 2; ++seg)
            #pragma unroll
            for (int s = 0; s < 2; ++s) {
                bf16x8 am0 = *(const bf16x8*)&Asm[A_IDX(seg, s, mf0,     r_slot)];
                bf16x8 am1 = *(const bf16x8*)&Asm[A_IDX(seg, s, mf0 + 1, r_slot)];
                bf16x8 bn0 = *(const bf16x8*)&Bsm[B_IDX(seg, s, nf0,     r_slot)];
                bf16x8 bn1 = *(const bf16x8*)&Bsm[B_IDX(seg, s, nf0 + 1, r_slot)];
                acc[0][0] = __builtin_amdgcn_mfma_f32_16x16x32_bf16(am0, bn0, acc[0][0], 0, 0, 0);
                acc[0][1] = __builtin_amdgcn_mfma_f32_16x16x32_bf16(am0, bn1, acc[0][1], 0, 0, 0);
                acc[1][0] = __builtin_amdgcn_mfma_f32_16x16x32_bf16(am1, bn0, acc[1][0], 0, 0, 0);
                acc[1][1] = __builtin_amdgcn_mfma_f32_16x16x32_bf16(am1, bn1, acc[1][1], 0, 0, 0);
            }
    }

    // reduce r_acc over the 16 staging threads sharing each o-row
    // (threads with equal t>>4 & i; consecutive 16 lanes -> in-wave shfl)
    #pragma unroll
    for (int d = 1; d < 16; d <<= 1) {
        #pragma unroll
        for (int i = 0; i < 4; ++i) r_acc[i] += __shfl_xor(r_acc[i], d);
    }
    __syncthreads();                             // LDS frags no longer needed
    if ((t & 15) == 0) {
        #pragma unroll
        for (int i = 0; i < 4; ++i) Rsm[i * 16 + (t >> 4)] = r_acc[i];
    }
    __syncthreads();

    // C/D: col = lane&15 (o), row = quad*4 + reg (b)  [m89-verified]
    const int col = lane & 15;
    #pragma unroll
    for (int mi = 0; mi < 2; ++mi) {
        int b = mBase + (wm * 2 + mi) * 16 + r_quad * 4;
        #pragma unroll
        for (int ni = 0; ni < 2; ++ni) {
            int oloc = (wn * 2 + ni) * 16 + col;
            int o = nBase + oloc;
            float rr = Rsm[oloc];
            #pragma unroll
            for (int r = 0; r < 4; ++r)
                part[((size_t)kz * B_SZ + (b + r)) * OUT_SZ + o] = acc[mi][ni][r] + rr;
        }
    }
}

// z = sum_kz part, out = a + exp(-z)*(1-2a). float4-vectorized.
__global__ __launch_bounds__(256) void rbf_reduce(
    const float* __restrict__ part, const float* __restrict__ andor,
    float* __restrict__ out)
{
    const int base = (blockIdx.x * 256 + threadIdx.x) * 4;
    if (base < B_SZ * OUT_SZ) {
        float4 z = make_float4(0.f, 0.f, 0.f, 0.f);
        #pragma unroll
        for (int kz = 0; kz < KSPLIT; ++kz) {
            const float4 p = *(const float4*)&part[(size_t)kz * (B_SZ * OUT_SZ) + base];
            z.x += p.x; z.y += p.y; z.z += p.z; z.w += p.w;
        }
        const float4 a = *(const float4*)&andor[base & (OUT_SZ - 1)];
        float4 o;
        o.x = fmaf(__expf(-z.x), 1.f - 2.f * a.x, a.x);
        o.y = fmaf(__expf(-z.y), 1.f - 2.f * a.y, a.y);
        o.z = fmaf(__expf(-z.z), 1.f - 2.f * a.z, a.z);
        o.w = fmaf(__expf(-z.w), 1.f - 2.f * a.w, a.w);
        *(float4*)&out[base] = o;
    }
}

extern "C" void kernel_launch(void* const* d_in, const int* in_sizes, int n_in,
                              void* d_out, int out_size, void* d_ws, size_t ws_size,
                              hipStream_t stream) {
    const float* x = (const float*)d_in[0];   // [B, IN]
    const float* w = (const float*)d_in[1];   // [OUT, IN]
    const float* u = (const float*)d_in[2];   // [OUT, IN]
    const float* a = (const float*)d_in[3];   // [1, OUT]
    float* out = (float*)d_out;               // [B, OUT]

    float* part = (float*)d_ws;               // [KSPLIT][B][OUT] f32 = 16 MB

    rbf_fused<<<dim3(16 * 8 * KSPLIT), dim3(256), 0, stream>>>(x, w, u, part);
    rbf_reduce<<<dim3(B_SZ * OUT_SZ / 4 / 256), dim3(256), 0, stream>>>(part, a, out);
}